// Round 9
// baseline (116.444 us; speedup 1.0000x reference)
//
#include <hip/hip_runtime.h>
#include <hip/hip_bf16.h>
#include <stdint.h>

typedef __bf16 bf16;
typedef __attribute__((ext_vector_type(8))) __bf16 bf16x8;
typedef __attribute__((ext_vector_type(4))) float f32x4;
typedef __attribute__((ext_vector_type(16))) float f32x16;

#define L2E 1.4426950408889634f

__device__ __forceinline__ f32x4 mfma16(bf16x8 a, bf16x8 b, f32x4 c) {
  return __builtin_amdgcn_mfma_f32_16x16x32_bf16(a, b, c, 0, 0, 0);
}

__device__ __forceinline__ f32x16 mfma32(bf16x8 a, bf16x8 b, f32x16 c) {
  return __builtin_amdgcn_mfma_f32_32x32x16_bf16(a, b, c, 0, 0, 0);
}

__device__ __forceinline__ void gload16(void* lds, const void* g) {
  __builtin_amdgcn_global_load_lds(
      (const __attribute__((address_space(1))) uint32_t*)g,
      (__attribute__((address_space(3))) uint32_t*)lds, 16, 0, 0);
}

__device__ __forceinline__ unsigned cvt_pk_bf16(float lo, float hi) {
  unsigned r;
  asm("v_cvt_pk_bf16_f32 %0, %1, %2" : "=v"(r) : "v"(lo), "v"(hi));
  return r;
}

// v_permlane32_swap_b32: a' = [a_lo | b_lo], b' = [a_hi | b_hi]
__device__ __forceinline__ void pl32swap(unsigned& a, unsigned& b) {
  auto r = __builtin_amdgcn_permlane32_swap(a, b, false, false);
  a = r[0];
  b = r[1];
}

// ---------------- prep: fp32 -> bf16 (+ fused RoPE tables) ----------------
__global__ __launch_bounds__(256) void prep_cast(
    const float* __restrict__ x, const float* __restrict__ wq,
    const float* __restrict__ wk, const float* __restrict__ wv,
    const float* __restrict__ wo, bf16* __restrict__ xb,
    bf16* __restrict__ wqb, bf16* __restrict__ wkb, bf16* __restrict__ wvb,
    bf16* __restrict__ wob, float* __restrict__ ct, float* __restrict__ st) {
  int blk = blockIdx.x;
  if (blk >= 8192) {  // RoPE tables: [2048][32] fp32
    int i = (blk - 8192) * 256 + threadIdx.x;  // 65536
    int t = i >> 5, d = i & 31;
    float inv = powf(10000.f, -(float)d * (1.f / 32.f));
    float a = (float)t * inv;
    ct[i] = cosf(a);
    st[i] = sinf(a);
    return;
  }
  int i = blk * 256 + threadIdx.x;  // unit of 4 floats
  const int NX = 4096 * 1024 / 4;
  const int NW = 1024 * 1024 / 4;
  const float* src; bf16* dst; int off;
  if (i < NX)               { src = x;  dst = xb;  off = i; }
  else if (i < NX + NW)     { src = wq; dst = wqb; off = i - NX; }
  else if (i < NX + 2 * NW) { src = wk; dst = wkb; off = i - (NX + NW); }
  else if (i < NX + 3 * NW) { src = wv; dst = wvb; off = i - (NX + 2 * NW); }
  else                      { src = wo; dst = wob; off = i - (NX + 3 * NW); }
  float4 v = ((const float4*)src)[off];
  union { bf16 h[4]; uint2 u; } o;
  o.h[0] = (bf16)v.x; o.h[1] = (bf16)v.y; o.h[2] = (bf16)v.z; o.h[3] = (bf16)v.w;
  ((uint2*)dst)[off] = o.u;
}

// ---------------- shared GEMM mainloop: C = A[4096x1024] * W^T[1024x1024] tile
// 128x128 tile, BK=32, 4 waves 2x2, double-buffered LDS, swizzled (rule #21)
__device__ __forceinline__ void gemm_mainloop(const bf16* __restrict__ A,
                                              const bf16* __restrict__ W,
                                              int m0, int n0,
                                              bf16 (*As)[4096], bf16 (*Bs)[4096],
                                              f32x4 acc[4][4]) {
  const int tid = threadIdx.x;
  const int lane = tid & 63, wave = tid >> 6;
  const int wr = (wave >> 1) * 64, wc = (wave & 1) * 64;
  const int lr = lane & 15, lh = lane >> 4;

  auto stage = [&](bf16* dA, bf16* dB, int kt) {
    int k0 = kt * 32;
#pragma unroll
    for (int p = 0; p < 2; p++) {
      int u = p * 256 + tid; int row = u >> 2; int kg = (u & 3) ^ (row & 3);
      gload16(dA + (size_t)u * 8, A + (size_t)(m0 + row) * 1024 + k0 + kg * 8);
    }
#pragma unroll
    for (int p = 0; p < 2; p++) {
      int u = p * 256 + tid; int row = u >> 2; int kg = (u & 3) ^ (row & 3);
      gload16(dB + (size_t)u * 8, W + (size_t)(n0 + row) * 1024 + k0 + kg * 8);
    }
  };

  stage(As[0], Bs[0], 0);
  int cur = 0;
  for (int kt = 0; kt < 32; ++kt) {
    __syncthreads();
    const bf16* cA = As[cur]; const bf16* cB = Bs[cur];
    bf16x8 af[4], bfr[4];
#pragma unroll
    for (int i = 0; i < 4; i++) {
      int row = wr + i * 16 + lr; int un = row * 4 + (lh ^ (row & 3));
      af[i] = *(const bf16x8*)(cA + (size_t)un * 8);
    }
#pragma unroll
    for (int j = 0; j < 4; j++) {
      int row = wc + j * 16 + lr; int un = row * 4 + (lh ^ (row & 3));
      bfr[j] = *(const bf16x8*)(cB + (size_t)un * 8);
    }
    if (kt + 1 < 32) stage(As[cur ^ 1], Bs[cur ^ 1], kt + 1);
#pragma unroll
    for (int i = 0; i < 4; i++)
#pragma unroll
      for (int j = 0; j < 4; j++) acc[i][j] = mfma16(af[i], bfr[j], acc[i][j]);
    cur ^= 1;
  }
}

// ---------------- QKV projection + RoPE epilogue + fused V^T --------------
// q/k: [32 bh][2048 t][64 d] bf16 (q pre-scaled by 0.125*log2e);
// V written DIRECTLY transposed: vt [32 bh][64 d][2048 t].
__global__ __launch_bounds__(256) void gemm_qkv(
    const bf16* __restrict__ xb, const bf16* __restrict__ wq,
    const bf16* __restrict__ wk, const bf16* __restrict__ wv,
    const float* __restrict__ ct, const float* __restrict__ st,
    bf16* __restrict__ qo, bf16* __restrict__ ko, bf16* __restrict__ vto) {
  __shared__ __align__(16) bf16 As[2][4096];
  __shared__ __align__(16) bf16 Bs[2][4096];
  int bm = blockIdx.x, bn = blockIdx.y;
  int proj = bn >> 3;
  const bf16* W = proj == 0 ? wq : (proj == 1 ? wk : wv);
  int m0 = bm * 128, n0 = (bn & 7) * 128;

  f32x4 zero = {0.f, 0.f, 0.f, 0.f};
  f32x4 acc[4][4];
#pragma unroll
  for (int i = 0; i < 4; i++)
#pragma unroll
    for (int j = 0; j < 4; j++) acc[i][j] = zero;

  gemm_mainloop(xb, W, m0, n0, As, Bs, acc);

  const int tid = threadIdx.x, lane = tid & 63, wave = tid >> 6;
  const int wr = (wave >> 1) * 64, wc = (wave & 1) * 64;
  const int lr = lane & 15, lh = lane >> 4;

  if (proj == 2) {
    // V^T direct write: 4 acc r-values are 4 consecutive t -> packed uint2
#pragma unroll
    for (int i = 0; i < 4; i++) {
      int t0 = m0 + wr + i * 16 + lh * 4;
      int b = t0 >> 11, tt = t0 & 2047;
#pragma unroll
      for (int j = 0; j < 4; j++) {
        int col = n0 + wc + j * 16 + lr;
        int h = col >> 6, d = col & 63;
        union { bf16 h4[4]; uint2 u; } pk4;
#pragma unroll
        for (int r = 0; r < 4; r++) pk4.h4[r] = (bf16)acc[i][j][r];
        *(uint2*)(vto + ((size_t)(b * 16 + h) * 64 + d) * 2048 + tt) = pk4.u;
      }
    }
    return;
  }

  bf16* out = proj == 0 ? qo : ko;
  int colb = n0 + wc;          // multiple of 64 -> single head per wave window
  int h = colb >> 6;
  const float QSC = 0.125f * L2E;  // fold softmax scale and log2(e) into Q
#pragma unroll
  for (int i = 0; i < 4; i++) {
#pragma unroll
    for (int r = 0; r < 4; r++) {
      int m = m0 + wr + i * 16 + lh * 4 + r;
      int b = m >> 11, t = m & 2047;
      float v0 = acc[i][0][r], v1 = acc[i][1][r];
      float v2 = acc[i][2][r], v3 = acc[i][3][r];
      {  // RoPE: pairs (d, d+32) are frags (0,2) and (1,3)
        float c0 = ct[t * 32 + lr],      s0 = st[t * 32 + lr];
        float c1 = ct[t * 32 + 16 + lr], s1 = st[t * 32 + 16 + lr];
        float n0v = v0 * c0 - v2 * s0, n2 = v2 * c0 + v0 * s0;
        float n1 = v1 * c1 - v3 * s1,  n3 = v3 * c1 + v1 * s1;
        v0 = n0v; v1 = n1; v2 = n2; v3 = n3;
        if (proj == 0) { v0 *= QSC; v1 *= QSC; v2 *= QSC; v3 *= QSC; }
      }
      size_t base = ((size_t)(b * 16 + h) * 2048 + t) * 64;
      out[base + lr]      = (bf16)v0;
      out[base + 16 + lr] = (bf16)v1;
      out[base + 32 + lr] = (bf16)v2;
      out[base + 48 + lr] = (bf16)v3;
    }
  }
}

// ---------------- flash attention v9 -------------------------------------
// One shared KV tile (64 kv) per block; 4 waves = (q-half sub) x (kv-chunk c).
// Per wave: 64 q x 32 kv per tile -> only 8 ds_read_b128/tile (the 32x32-MFMA
// floor). 3-buffer LDS rotation (48 KB) + counted s_waitcnt vmcnt(4) + one raw
// s_barrier per tile: stage(t+2) loads stay in flight across two tiles.
// Static-max softmax (v5 derivation): c-merge = pure (acc,l) sum via LDS.
// grid 512 = 32 bh x 16 qt (128 q/block); 2 blocks/CU. Q pre-scaled.
// k: [bh][t][64]; vt: [bh][d][2048].
__global__ __launch_bounds__(256, 2) void attn(const bf16* __restrict__ q,
                                               const bf16* __restrict__ k,
                                               const bf16* __restrict__ vt,
                                               bf16* __restrict__ o) {
  __shared__ __align__(16) char smb[49152];  // 3 bufs x (K 8KB + V 8KB)
  // chunked XCD swizzle (512 % 8 == 0 -> bijective): 4 whole bh per XCD
  int pidx = blockIdx.x;
  int L = (pidx & 7) * 64 + (pidx >> 3);
  int bh = L >> 4, qt = L & 15;

  const int tid = threadIdx.x, lane = tid & 63, wave = tid >> 6;
  const int lq = lane & 31, hi = lane >> 5;
  const int sub = wave & 1;  // q half (64 rows)
  const int c = wave >> 1;   // kv chunk of each tile (32 rows)

  const bf16* kg = k + (size_t)bh * 131072;   // [2048 kv][64 d]
  const bf16* vg = vt + (size_t)bh * 131072;  // [64 d][2048 kv]

  // Q B-frags: qf[qb][kk]: Q[q0 + qb*32 + lq][kk*16 + hi*8 + j]
  int q0 = qt * 128 + sub * 64;
  const bf16* qbp = q + ((size_t)bh * 2048 + q0) * 64;
  bf16x8 qf[2][4];
#pragma unroll
  for (int qb = 0; qb < 2; qb++)
#pragma unroll
    for (int kk = 0; kk < 4; kk++)
      qf[qb][kk] =
          *(const bf16x8*)(qbp + (size_t)(qb * 32 + lq) * 64 + kk * 16 + hi * 8);

  // LDS read vaddrs (bytes within a buffer; 128B rows, 8-unit XOR swizzle)
  int vaK[4];
  {
    int rowK = c * 32 + lq;
#pragma unroll
    for (int kk = 0; kk < 4; kk++)
      vaK[kk] = rowK * 128 + (((2 * kk + hi) ^ (rowK & 7)) << 4);
  }
  int vaV[2][2];  // [cc][db]
#pragma unroll
  for (int cc = 0; cc < 2; cc++)
#pragma unroll
    for (int db = 0; db < 2; db++)
      vaV[cc][db] = 8192 + (db * 32 + lq) * 128 +
                    (((4 * c + 2 * cc + hi) ^ (lq & 7)) << 4);

  // staging: 256 threads x 4 units (2 K + 2 V); pre-swizzled source (rule #21)
  int kofe[2], vofe[2], ldsK[2], ldsV[2];
#pragma unroll
  for (int pp = 0; pp < 2; pp++) {
    int uu = pp * 256 + tid;
    int r = uu >> 3, lu = uu & 7, su = lu ^ (r & 7);
    kofe[pp] = r * 64 + su * 8;    // + t*4096
    vofe[pp] = r * 2048 + su * 8;  // + t*64
    ldsK[pp] = uu * 16;
    ldsV[pp] = 8192 + uu * 16;
  }

  f32x16 acc[2][2];  // [qb][db]
  f32x16 CM;         // persistent MFMA C-init: all -16 (static max)
#pragma unroll
  for (int r = 0; r < 16; r++) {
    acc[0][0][r] = 0.f; acc[0][1][r] = 0.f;
    acc[1][0][r] = 0.f; acc[1][1][r] = 0.f;
    CM[r] = -16.f;
  }
  float l0 = 0.f, l1 = 0.f;

  auto stage = [&](int bo, int t) {
#pragma unroll
    for (int pp = 0; pp < 2; pp++) {
      gload16(smb + bo + ldsK[pp], kg + t * 4096 + kofe[pp]);
      gload16(smb + bo + ldsV[pp], vg + t * 64 + vofe[pp]);
    }
  };

  auto compute = [&](int bo) {
    bf16x8 ka[4], vv[2][2];
#pragma unroll
    for (int kk = 0; kk < 4; kk++)
      ka[kk] = *(const bf16x8*)(smb + bo + vaK[kk]);
#pragma unroll
    for (int cc = 0; cc < 2; cc++)
#pragma unroll
      for (int db = 0; db < 2; db++)
        vv[cc][db] = *(const bf16x8*)(smb + bo + vaV[cc][db]);

    __builtin_amdgcn_s_setprio(1);
    f32x16 s0 = mfma32(ka[0], qf[0][0], CM);
    f32x16 s1 = mfma32(ka[0], qf[1][0], CM);
#pragma unroll
    for (int kk = 1; kk < 4; kk++) {
      s0 = mfma32(ka[kk], qf[0][kk], s0);
      s1 = mfma32(ka[kk], qf[1][kk], s1);
    }
    __builtin_amdgcn_s_setprio(0);

    unsigned pk0[8], pk1[8];
    {
      float sa = 0.f, sb = 0.f;
#pragma unroll
      for (int i = 0; i < 8; i++) {
        float pa = __builtin_amdgcn_exp2f(s0[2 * i]);
        float pb = __builtin_amdgcn_exp2f(s0[2 * i + 1]);
        sa += pa; sb += pb;
        pk0[i] = cvt_pk_bf16(pa, pb);
      }
      l0 += sa + sb;
    }
    {
      float sa = 0.f, sb = 0.f;
#pragma unroll
      for (int i = 0; i < 8; i++) {
        float pa = __builtin_amdgcn_exp2f(s1[2 * i]);
        float pb = __builtin_amdgcn_exp2f(s1[2 * i + 1]);
        sa += pa; sb += pb;
        pk1[i] = cvt_pk_bf16(pa, pb);
      }
      l1 += sa + sb;
    }

    pl32swap(pk0[0], pk0[2]); pl32swap(pk0[1], pk0[3]);
    pl32swap(pk0[4], pk0[6]); pl32swap(pk0[5], pk0[7]);
    pl32swap(pk1[0], pk1[2]); pl32swap(pk1[1], pk1[3]);
    pl32swap(pk1[4], pk1[6]); pl32swap(pk1[5], pk1[7]);

    __builtin_amdgcn_s_setprio(1);
#pragma unroll
    for (int cc = 0; cc < 2; cc++) {
      union { unsigned u[4]; bf16x8 v; } pb0, pb1;
#pragma unroll
      for (int w = 0; w < 4; w++) {
        pb0.u[w] = pk0[4 * cc + w];
        pb1.u[w] = pk1[4 * cc + w];
      }
#pragma unroll
      for (int db = 0; db < 2; db++) {
        acc[0][db] = mfma32(vv[cc][db], pb0.v, acc[0][db]);
        acc[1][db] = mfma32(vv[cc][db], pb1.v, acc[1][db]);
      }
    }
    __builtin_amdgcn_s_setprio(0);
  };

  // -------- counted-vmcnt 3-buffer main loop --------
  stage(0, 0);
  stage(16384, 1);
  int boC = 0, boS = 32768;
  for (int t = 0; t < 31; ++t) {
    asm volatile("s_waitcnt vmcnt(4)" ::: "memory");  // stage(t) landed (own)
    __builtin_amdgcn_s_barrier();                     // all waves: tile t ready
    if (t + 2 < 32) stage(boS, t + 2);
    compute(boC);
    boC += 16384; if (boC == 49152) boC = 0;
    boS += 16384; if (boS == 49152) boS = 0;
  }
  asm volatile("s_waitcnt vmcnt(0)" ::: "memory");
  __builtin_amdgcn_s_barrier();
  compute(boC);  // tile 31

  // -------- c-merge: c==1 deposits (acc, l); c==0 sums --------
  __syncthreads();
  float* abuf = (float*)smb;             // 32 KB exact
  float* lbuf = (float*)(smb + 32768);   // 1 KB
  if (c == 1) {
#pragma unroll
    for (int qb = 0; qb < 2; qb++)
#pragma unroll
      for (int db = 0; db < 2; db++)
#pragma unroll
        for (int r = 0; r < 16; r++)
          abuf[((sub * 4 + qb * 2 + db) * 16 + r) * 64 + lane] = acc[qb][db][r];
    lbuf[(sub * 2 + 0) * 64 + lane] = l0;
    lbuf[(sub * 2 + 1) * 64 + lane] = l1;
  }
  __syncthreads();
  if (c == 1) return;
#pragma unroll
  for (int qb = 0; qb < 2; qb++)
#pragma unroll
    for (int db = 0; db < 2; db++)
#pragma unroll
      for (int r = 0; r < 16; r++)
        acc[qb][db][r] += abuf[((sub * 4 + qb * 2 + db) * 16 + r) * 64 + lane];
  l0 += lbuf[(sub * 2 + 0) * 64 + lane];
  l1 += lbuf[(sub * 2 + 1) * 64 + lane];

  // -------- epilogue: lane-half l merge, O[q][d] = acc^T / l --------
  {
    unsigned ta = __float_as_uint(l0), tb = ta;
    pl32swap(ta, tb);
    l0 = __uint_as_float(ta) + __uint_as_float(tb);
  }
  {
    unsigned ta = __float_as_uint(l1), tb = ta;
    pl32swap(ta, tb);
    l1 = __uint_as_float(ta) + __uint_as_float(tb);
  }
  float inv[2] = {1.0f / l0, 1.0f / l1};
  int b = bh >> 4, h = bh & 15;
#pragma unroll
  for (int qb = 0; qb < 2; qb++) {
    int qrow = q0 + qb * 32 + lq;
    bf16* orow = o + ((size_t)(b * 2048 + qrow)) * 1024 + h * 64;
#pragma unroll
    for (int db = 0; db < 2; db++)
#pragma unroll
      for (int g = 0; g < 4; g++) {
        union { bf16 h4[4]; uint2 u; } t;
#pragma unroll
        for (int e = 0; e < 4; e++)
          t.h4[e] = (bf16)(acc[qb][db][4 * g + e] * inv[qb]);
        *(uint2*)(orow + db * 32 + 8 * g + 4 * hi) = t.u;
      }
  }
}

// ---------------- output projection: fp32 epilogue into d_out ----------------
__global__ __launch_bounds__(256) void gemm_out(const bf16* __restrict__ ab,
                                                const bf16* __restrict__ wo,
                                                float* __restrict__ out) {
  __shared__ __align__(16) bf16 As[2][4096];
  __shared__ __align__(16) bf16 Bs[2][4096];
  int m0 = blockIdx.x * 128, n0 = blockIdx.y * 128;
  f32x4 zero = {0.f, 0.f, 0.f, 0.f};
  f32x4 acc[4][4];
#pragma unroll
  for (int i = 0; i < 4; i++)
#pragma unroll
    for (int j = 0; j < 4; j++) acc[i][j] = zero;

  gemm_mainloop(ab, wo, m0, n0, As, Bs, acc);

  const int tid = threadIdx.x, lane = tid & 63, wave = tid >> 6;
  const int wr = (wave >> 1) * 64, wc = (wave & 1) * 64;
  const int lr = lane & 15, lh = lane >> 4;
#pragma unroll
  for (int i = 0; i < 4; i++)
#pragma unroll
    for (int r = 0; r < 4; r++) {
      int m = m0 + wr + i * 16 + lh * 4 + r;
#pragma unroll
      for (int j = 0; j < 4; j++) {
        int col = n0 + wc + j * 16 + lr;
        out[(size_t)m * 1024 + col] = acc[i][j][r];
      }
    }
}

extern "C" void kernel_launch(void* const* d_in, const int* in_sizes, int n_in,
                              void* d_out, int out_size, void* d_ws, size_t ws_size,
                              hipStream_t stream) {
  const float* x  = (const float*)d_in[0];
  const float* wq = (const float*)d_in[1];
  const float* wk = (const float*)d_in[2];
  const float* wv = (const float*)d_in[3];
  const float* wo = (const float*)d_in[4];
  float* out = (float*)d_out;
  char* ws = (char*)d_ws;
  const size_t MB = 1u << 20;
  bf16* xb  = (bf16*)(ws + 0);
  bf16* wqb = (bf16*)(ws + 8 * MB);
  bf16* wkb = (bf16*)(ws + 10 * MB);
  bf16* wvb = (bf16*)(ws + 12 * MB);
  bf16* wob = (bf16*)(ws + 14 * MB);
  bf16* qw  = (bf16*)(ws + 16 * MB);
  bf16* kw  = (bf16*)(ws + 24 * MB);
  bf16* vtw = (bf16*)(ws + 32 * MB);
  bf16* aw  = (bf16*)(ws + 40 * MB);
  float* ct = (float*)(ws + 48 * MB);
  float* st = (float*)(ws + 48 * MB + 256 * 1024);

  prep_cast<<<8448, 256, 0, stream>>>(x, wq, wk, wv, wo, xb, wqb, wkb, wvb,
                                      wob, ct, st);
  gemm_qkv<<<dim3(32, 24), 256, 0, stream>>>(xb, wqb, wkb, wvb, ct, st, qw, kw,
                                             vtw);
  attn<<<512, 256, 0, stream>>>(qw, kw, vtw, aw);
  gemm_out<<<dim3(32, 8), 256, 0, stream>>>(aw, wob, out);
}